// Round 13
// baseline (6078.467 us; speedup 1.0000x reference)
//
#include <hip/hip_runtime.h>
#include <math.h>

#define E 256
#define Hh 512

typedef __attribute__((ext_vector_type(8))) short short8;
typedef __attribute__((ext_vector_type(4))) float f32x4;

// R13: XCD-aware swizzle (per-XCD L2-resident weight slices) + coalesced out_kernel
// (transposed bf16 Wf) + fully-unrolled K-phases. Data flow identical to R12 (PASS).

struct LstmP {
  const int* ids;
  const float* emb;            // f32 emb table (cvt to bf16 in-kernel)
  const unsigned short* Wih;   // bf16 ws cache [2048,256]
  const unsigned short* Whh;   // bf16 ws cache [2048,512]
  const float* bias;           // f32 [2048]
  const unsigned short* h_in;  // [N,512] bf16 ws
  unsigned short* h_out;       // [N,512] bf16 ws
  float* c;                    // [N,512] f32 ws
  int T;
};

__device__ __forceinline__ float bf2f(unsigned short x){
  union { unsigned u; float f; } v; v.u = ((unsigned)x) << 16; return v.f;
}
__device__ __forceinline__ unsigned short f2bf(float f){
  union { float f; unsigned u; } v; v.f = f;
  unsigned u = v.u;
  return (unsigned short)((u + 0x7fffu + ((u >> 16) & 1u)) >> 16);
}
__device__ __forceinline__ short8 cvt8(const float* p){
  f32x4 x = *(const f32x4*)p;
  f32x4 y = *(const f32x4*)(p + 4);
  short8 r;
  r[0]=(short)f2bf(x[0]); r[1]=(short)f2bf(x[1]); r[2]=(short)f2bf(x[2]); r[3]=(short)f2bf(x[3]);
  r[4]=(short)f2bf(y[0]); r[5]=(short)f2bf(y[1]); r[6]=(short)f2bf(y[2]); r[7]=(short)f2bf(y[3]);
  return r;
}
__device__ __forceinline__ float sigm(float x){ return 1.0f/(1.0f + expf(-x)); }

__global__ void zero_ws_kernel(uint4* p, int n){
  int i = blockIdx.x*256 + threadIdx.x;
  if (i < n){ uint4 z; z.x=0u; z.y=0u; z.z=0u; z.w=0u; p[i]=z; }
}

__global__ __launch_bounds__(256) void cvt_kernel(const float* src, unsigned short* dst, int n8){
  int i = blockIdx.x*256 + threadIdx.x;
  if (i < n8) *(short8*)(dst + (size_t)i*8) = cvt8(src + (size_t)i*8);
}

// Wf [512,522] f32 -> Wft [522,512] bf16 (coalesced writes)
__global__ __launch_bounds__(256) void transpose_wf_kernel(const float* W, unsigned short* Wt){
  int idx = blockIdx.x*256 + threadIdx.x;
  if (idx < 522*512){
    int k = idx >> 9, u = idx & 511;
    Wt[idx] = f2bf(W[(size_t)u*522 + k]);
  }
}

// One time-step. XCD-aware mapping: x = blockIdx%8 (XCD heuristic), s = blockIdx/8.
// XCD 0-3: sc, j-tiles [x*4, x*4+4) x 10 m-blocks. XCD 4-7: cm same (t<64) + is
// j-tiles (t<32). Per-XCD weight slice: sc 0.75 MB / cm 0.75 + is 0.75 MB -> L2-resident.
__global__ __launch_bounds__(256, 2) void lstm_step_kernel(LstmP sc, LstmP cm, LstmP is, int t)
{
  __shared__ float zb[4][64][32];   // 32 KB; swizzled (<=2-way, free)
  LstmP P; int mb, jt;
  {
    const int x = blockIdx.x & 7;
    const int s = blockIdx.x >> 3;
    if (x < 4){
      if (s >= 40) return;
      P = sc; jt = x*4 + (s/10); mb = s - (s/10)*10;
    } else {
      if (s < 40){
        if (t >= 64) return;
        P = cm; jt = (x-4)*4 + (s/10); mb = s - (s/10)*10;
      } else if (s < 44){
        if (t >= 32) return;
        P = is; jt = (x-4)*4 + (s-40); mb = 0;
      } else return;
    }
  }
  const int tid  = threadIdx.x;
  const int w    = tid >> 6;       // gate 0..3 = i,f,g,o
  const int lane = tid & 63;
  const int l15  = lane & 15;
  const int q    = lane >> 4;
  const int m0 = mb*64, j0 = jt*32;

  const float* ap1[4];
  const unsigned short* ap2[4];
  #pragma unroll
  for (int mi=0; mi<4; ++mi){
    int m = m0 + mi*16 + l15;
    int id = P.ids[m*P.T + t];
    ap1[mi] = P.emb  + (size_t)id*E + q*8;
    ap2[mi] = P.h_in + (size_t)m*Hh + q*8;
  }
  const unsigned short* bp1[2];
  const unsigned short* bp2[2];
  #pragma unroll
  for (int ni=0; ni<2; ++ni){
    int n = w*Hh + j0 + ni*16 + l15;
    bp1[ni] = P.Wih + (size_t)n*E  + q*8;
    bp2[ni] = P.Whh + (size_t)n*Hh + q*8;
  }

  f32x4 acc[4][2];
  #pragma unroll
  for (int i=0;i<4;++i)
    #pragma unroll
    for (int j=0;j<2;++j) acc[i][j] = (f32x4){0.f,0.f,0.f,0.f};

  // Phase 1: K=0..255 (emb cvt f32->bf16 x Wih). Fully unrolled for load ILP.
  #pragma unroll
  for (int kc=0; kc<8; ++kc){
    short8 a[4], b[2];
    #pragma unroll
    for (int mi=0;mi<4;++mi) a[mi] = cvt8(ap1[mi] + kc*32);
    #pragma unroll
    for (int ni=0;ni<2;++ni) b[ni] = *(const short8*)(bp1[ni] + kc*32);
    #pragma unroll
    for (int mi=0;mi<4;++mi)
      #pragma unroll
      for (int ni=0;ni<2;++ni)
        acc[mi][ni] = __builtin_amdgcn_mfma_f32_16x16x32_bf16(a[mi], b[ni], acc[mi][ni], 0,0,0);
  }
  // Phase 2: K=256..767 (h bf16 x Whh bf16). Fully unrolled.
  #pragma unroll
  for (int kc=0; kc<16; ++kc){
    short8 a[4], b[2];
    #pragma unroll
    for (int mi=0;mi<4;++mi) a[mi] = *(const short8*)(ap2[mi] + kc*32);
    #pragma unroll
    for (int ni=0;ni<2;++ni) b[ni] = *(const short8*)(bp2[ni] + kc*32);
    #pragma unroll
    for (int mi=0;mi<4;++mi)
      #pragma unroll
      for (int ni=0;ni<2;++ni)
        acc[mi][ni] = __builtin_amdgcn_mfma_f32_16x16x32_bf16(a[mi], b[ni], acc[mi][ni], 0,0,0);
  }

  float bv[2];
  #pragma unroll
  for (int ni=0;ni<2;++ni) bv[ni] = P.bias[w*Hh + j0 + ni*16 + l15];

  // C/D layout: row = q*4+r, col = l15 (m89-verified, R12-pass-verified)
  #pragma unroll
  for (int mi=0;mi<4;++mi)
    #pragma unroll
    for (int ni=0;ni<2;++ni)
      #pragma unroll
      for (int r=0;r<4;++r){
        int m = mi*16 + q*4 + r;
        int col = (ni*16 + l15 + q*8) & 31;
        zb[w][m][col] = acc[mi][ni][r] + bv[ni];
      }
  __syncthreads();

  for (int e = tid; e < 64*32; e += 256){
    int m = e >> 5, j = e & 31;
    int cs = (j + ((m>>2)&3)*8) & 31;
    float zi = zb[0][m][cs], zf = zb[1][m][cs], zg = zb[2][m][cs], zo = zb[3][m][cs];
    int gi = (m0 + m)*Hh + j0 + j;
    float cold = P.c[gi];
    float cn = sigm(zf)*cold + sigm(zi)*tanhf(zg);
    float hn = sigm(zo)*tanhf(cn);
    P.c[gi] = cn;
    P.h_out[gi] = f2bf(hn);
  }
}

// Coalesced output kernel. Grid 128 = (b, kind). x (522) staged in LDS;
// final GEMM streams transposed bf16 Wft[k][u] (consecutive u = consecutive addr).
__global__ __launch_bounds__(256) void out_kernel(
    const unsigned short* hsc, const unsigned short* hcm, const unsigned short* his,
    const float* csc, const float* ccm, const float* cis,
    const float* Wmh, const float* bmh, const float* Wmc, const float* bmc,
    const unsigned short* Wfh_t, const float* bfh,
    const unsigned short* Wfc_t, const float* bfc,
    float* out)
{
  const int b = blockIdx.x >> 1, kind = blockIdx.x & 1, tid = threadIdx.x;
  const float* Wm = kind ? Wmc : Wmh;
  const float* bm = kind ? bmc : bmh;
  const unsigned short* Wt = kind ? Wfc_t : Wfh_t;
  const float* bf = kind ? bfc : bfh;

  __shared__ float xv[522];   // [hm(10) | state(512)]
  for (int k = tid; k < 512; k += 256)
    xv[10+k] = kind ? cis[(size_t)b*512+k] : bf2f(his[(size_t)b*512+k]);

  const int wv = tid >> 6, lane = tid & 63;
  for (int nc = wv; nc < 10; nc += 4){
    size_t n = (size_t)b*10 + nc;
    float a = 0.f;
    for (int k = lane; k < 512; k += 64){
      float v1 = kind ? csc[n*512+k] : bf2f(hsc[n*512+k]);
      float v2 = kind ? ccm[n*512+k] : bf2f(hcm[n*512+k]);
      a += Wm[k]*v1 + Wm[512+k]*v2;
    }
    #pragma unroll
    for (int off=32; off>0; off>>=1) a += __shfl_down(a, off);
    if (lane == 0) xv[nc] = a + bm[0];
  }
  __syncthreads();

  #pragma unroll
  for (int uu=0; uu<2; ++uu){
    int u = tid + 256*uu;
    float acc = bf[u];
    #pragma unroll 6
    for (int k=0;k<522;++k) acc += bf2f(Wt[(size_t)k*512+u]) * xv[k];
    out[(size_t)kind*32768 + (size_t)b*512 + u] = acc;
  }
}

extern "C" void kernel_launch(void* const* d_in, const int* in_sizes, int n_in,
                              void* d_out, int out_size, void* d_ws, size_t ws_size,
                              hipStream_t stream) {
  const int* comments = (const int*)d_in[0];
  const int* cm_ids   = (const int*)d_in[1];
  const int* issue    = (const int*)d_in[2];
  const float* emb_sc = (const float*)d_in[3];
  const float* emb_cm = (const float*)d_in[4];
  const float* emb_is = (const float*)d_in[5];
  const float* Wih_sc = (const float*)d_in[6];
  const float* Whh_sc = (const float*)d_in[7];
  const float* b_sc   = (const float*)d_in[8];
  const float* Wih_cm = (const float*)d_in[9];
  const float* Whh_cm = (const float*)d_in[10];
  const float* b_cm   = (const float*)d_in[11];
  const float* Wih_is = (const float*)d_in[12];
  const float* Whh_is = (const float*)d_in[13];
  const float* b_is   = (const float*)d_in[14];
  const float* Wmh = (const float*)d_in[15];
  const float* bmh = (const float*)d_in[16];
  const float* Wmc = (const float*)d_in[17];
  const float* bmc = (const float*)d_in[18];
  const float* Wfh = (const float*)d_in[19];
  const float* bfh = (const float*)d_in[20];
  const float* Wfc = (const float*)d_in[21];
  const float* bfc = (const float*)d_in[22];

  // Workspace (~16.0 MB; 14.94 MB extent proven by R3/R12, +1.07 MB transposed Wf)
  char* p = (char*)d_ws;
  unsigned short* hb_sc = (unsigned short*)p; p += (size_t)2*640*512*2;
  unsigned short* hb_cm = (unsigned short*)p; p += (size_t)2*640*512*2;
  unsigned short* hb_is = (unsigned short*)p; p += (size_t)2*64*512*2;
  float* c_sc = (float*)p; p += (size_t)640*512*4;
  float* c_cm = (float*)p; p += (size_t)640*512*4;
  float* c_is = (float*)p; p += (size_t)64*512*4;
  size_t zero_bytes = (size_t)(p - (char*)d_ws);
  unsigned short* Wih_sc_b = (unsigned short*)p; p += (size_t)2048*256*2;
  unsigned short* Whh_sc_b = (unsigned short*)p; p += (size_t)2048*512*2;
  unsigned short* Wih_cm_b = (unsigned short*)p; p += (size_t)2048*256*2;
  unsigned short* Whh_cm_b = (unsigned short*)p; p += (size_t)2048*512*2;
  unsigned short* Wih_is_b = (unsigned short*)p; p += (size_t)2048*256*2;
  unsigned short* Whh_is_b = (unsigned short*)p; p += (size_t)2048*512*2;
  unsigned short* Wfh_t = (unsigned short*)p; p += (size_t)522*512*2;
  unsigned short* Wfc_t = (unsigned short*)p; p += (size_t)522*512*2;

  int n4 = (int)(zero_bytes/16);
  zero_ws_kernel<<<(n4+255)/256, 256, 0, stream>>>((uint4*)d_ws, n4);

  const int nih8 = 2048*256/8, nhh8 = 2048*512/8;
  cvt_kernel<<<(nih8+255)/256, 256, 0, stream>>>(Wih_sc, Wih_sc_b, nih8);
  cvt_kernel<<<(nhh8+255)/256, 256, 0, stream>>>(Whh_sc, Whh_sc_b, nhh8);
  cvt_kernel<<<(nih8+255)/256, 256, 0, stream>>>(Wih_cm, Wih_cm_b, nih8);
  cvt_kernel<<<(nhh8+255)/256, 256, 0, stream>>>(Whh_cm, Whh_cm_b, nhh8);
  cvt_kernel<<<(nih8+255)/256, 256, 0, stream>>>(Wih_is, Wih_is_b, nih8);
  cvt_kernel<<<(nhh8+255)/256, 256, 0, stream>>>(Whh_is, Whh_is_b, nhh8);
  const int ntr = (522*512 + 255)/256;
  transpose_wf_kernel<<<ntr, 256, 0, stream>>>(Wfh, Wfh_t);
  transpose_wf_kernel<<<ntr, 256, 0, stream>>>(Wfc, Wfc_t);

  for (int t = 0; t < 128; ++t){
    LstmP Psc = { comments, emb_sc, Wih_sc_b, Whh_sc_b, b_sc,
                  hb_sc + (size_t)(t&1)*640*512, hb_sc + (size_t)((t+1)&1)*640*512,
                  c_sc, 128 };
    LstmP Pcm = { cm_ids, emb_cm, Wih_cm_b, Whh_cm_b, b_cm,
                  hb_cm + (size_t)(t&1)*640*512, hb_cm + (size_t)((t+1)&1)*640*512,
                  c_cm, 64 };
    LstmP Pis = { issue, emb_is, Wih_is_b, Whh_is_b, b_is,
                  hb_is + (size_t)(t&1)*64*512, hb_is + (size_t)((t+1)&1)*64*512,
                  c_is, 32 };
    lstm_step_kernel<<<352, 256, 0, stream>>>(Psc, Pcm, Pis, t);
  }

  // Final h states in buffer 0 (sc t=127 -> (128&1)=0; cm t=63; is t=31).
  out_kernel<<<128, 256, 0, stream>>>(hb_sc, hb_cm, hb_is, c_sc, c_cm, c_is,
                                      Wmh, bmh, Wmc, bmc, Wfh_t, bfh, Wfc_t, bfc,
                                      (float*)d_out);
}